// Round 4
// baseline (4158.441 us; speedup 1.0000x reference)
//
#include <hip/hip_runtime.h>
#include <hip/hip_bf16.h>
#include <cstdint>
#include <cstddef>

// ---------------------------------------------------------------------------
// AudioEncoder (Whisper-style) forward for MI355X.
// B=8, T=4096, n_mels=128, D=1024, H=8 heads (hd=128), F=4096, L=6, S=1024.
// GEMMs: bf16 MFMA 128x128 tile, 2-phase double-buffered LDS.
// Attention: fused flash kernel (no score materialization, no barriers).
// ---------------------------------------------------------------------------

typedef __bf16 bf16_t;
typedef __bf16 bf16x8 __attribute__((ext_vector_type(8)));
typedef __bf16 bf16x4 __attribute__((ext_vector_type(4)));
typedef float  floatx4 __attribute__((ext_vector_type(4)));

#define NB   8
#define NS   1024
#define ND   1024
#define NT   4096
#define NT1  2048

#define MFMA16(a, b, c) __builtin_amdgcn_mfma_f32_16x16x32_bf16(a, b, c, 0, 0, 0)

__device__ __forceinline__ float gelu_f(float x) {
  return 0.5f * x * (1.0f + erff(x * 0.70710678118654752440f));
}

__device__ __forceinline__ void gload16(const void* g, void* l) {
  __builtin_amdgcn_global_load_lds(
      (__attribute__((address_space(1))) void*)(const_cast<void*>(g)),
      (__attribute__((address_space(3))) void*)l, 16, 0, 0);
}

enum { EPI_BF16 = 0, EPI_GELU_BF16 = 2, EPI_GELU_F32 = 3, EPI_RES_F32 = 4, EPI_QKV = 5 };

// C = A (M,K) @ B^T, B stored (N,K) row-major. 128x128 tile, 4 waves, each a
// 64x64 quadrant of 4x4 16x16x32-bf16 MFMA frags. 2-phase double-buffered LDS.
template<int EPI>
__global__ __launch_bounds__(256)
void gemm_bt(const bf16_t* __restrict__ A, long lda, long aHi, long aLo,
             const bf16_t* __restrict__ Bm, long ldb, long bHi, long bLo,
             void* Cv, long ldc, long cHi, long cLo,
             const float* __restrict__ bias, const float* res,
             int K, int bMod, int swz,
             bf16_t* out2, bf16_t* out3, const float* __restrict__ bias2,
             const float2* __restrict__ rtab)
{
  __shared__ bf16_t sA[2][128 * 32];
  __shared__ bf16_t sB[2][128 * 32];
  const int tid  = threadIdx.x;
  const int w    = tid >> 6;
  const int lane = tid & 63;
  const int z  = blockIdx.z;
  const int zq = z / bMod, zr = z % bMod;
  const bf16_t* Ab = A  + (long)zq * aHi + (long)zr * aLo;
  const bf16_t* Bb = Bm + (long)zq * bHi + (long)zr * bLo;
  const long offC  = (long)zq * cHi + (long)zr * cLo;

  int bx = blockIdx.x, by = blockIdx.y;
  if (swz) {               // bijective XCD-chunked remap (grid size % 8 == 0)
    const int gx = gridDim.x;
    const int n  = gx * gridDim.y;
    int id = bx + by * gx;
    id = (id & 7) * (n >> 3) + (id >> 3);
    bx = id % gx; by = id / gx;
  }
  const int m0 = bx * 128, n0 = by * 128;

  const int lrow = lane >> 2;        // 0..15
  const int lcol = (lane & 3) * 8;   // elem offset 0,8,16,24
  const int seg0 = w * 2;

  floatx4 acc[4][4] = {};
  const int wr = w >> 1, wc = w & 1;

  auto stage = [&](int kb, int buf) {
#pragma unroll
    for (int j = 0; j < 2; ++j) {
      const int seg = seg0 + j;
      gload16(Ab + (long)(m0 + seg * 16 + lrow) * lda + (kb + lcol), &sA[buf][seg * 512]);
      gload16(Bb + (long)(n0 + seg * 16 + lrow) * ldb + (kb + lcol), &sB[buf][seg * 512]);
    }
  };

  stage(0, 0);
  __syncthreads();
  int cur = 0;
  for (int kb = 0; kb < K; kb += 32) {
    if (kb + 32 < K) stage(kb + 32, cur ^ 1);
    bf16x8 av[4], bv[4];
#pragma unroll
    for (int i = 0; i < 4; ++i) {
      av[i] = *reinterpret_cast<const bf16x8*>(
          &sA[cur][(wr * 64 + i * 16 + (lane & 15)) * 32 + (lane >> 4) * 8]);
      bv[i] = *reinterpret_cast<const bf16x8*>(
          &sB[cur][(wc * 64 + i * 16 + (lane & 15)) * 32 + (lane >> 4) * 8]);
    }
#pragma unroll
    for (int mi = 0; mi < 4; ++mi)
#pragma unroll
      for (int ni = 0; ni < 4; ++ni)
        acc[mi][ni] = MFMA16(av[mi], bv[ni], acc[mi][ni]);
    __syncthreads();
    cur ^= 1;
  }

  if constexpr (EPI == EPI_QKV) {
    const int sect = n0 >> 10;        // 0=Q 1=K 2=V
#pragma unroll
    for (int ni = 0; ni < 4; ++ni) {
      const int col = n0 + wc * 64 + ni * 16 + (lane & 15);
      const int c10 = col & 1023;
      float bvs = 0.0f;
      if (sect == 0) bvs = bias[c10];
      else if (sect == 2) bvs = bias2[c10];
#pragma unroll
      for (int mi = 0; mi < 4; ++mi) {
#pragma unroll
        for (int r = 0; r < 4; ++r) {
          const int row = m0 + wr * 64 + mi * 16 + (lane >> 4) * 4 + r;
          const int s = row & 1023;
          float val = acc[mi][ni][r] + bvs;
          if (sect < 2) {             // rope + scale (table pre-scaled)
            const float2 t = rtab[(s << 6) + ((col & 127) >> 1)];
            const float p = __shfl_xor(val, 1);
            val = val * t.x + p * ((col & 1) ? t.y : -t.y);
            bf16_t* dst = sect ? out2 : (bf16_t*)Cv;
            dst[(long)row * 1024 + c10] = (bf16_t)val;
          } else {                    // vt[b][h*128+d][s]
            out3[((long)(row >> 10) << 20) + ((long)(col - 2048) << 10) + s] = (bf16_t)val;
          }
        }
      }
    }
    return;
  }

#pragma unroll
  for (int ni = 0; ni < 4; ++ni) {
    const int col = n0 + wc * 64 + ni * 16 + (lane & 15);
    const float bvs = bias ? bias[col] : 0.0f;
#pragma unroll
    for (int mi = 0; mi < 4; ++mi) {
#pragma unroll
      for (int r = 0; r < 4; ++r) {
        const int row = m0 + wr * 64 + mi * 16 + (lane >> 4) * 4 + r;
        float v = acc[mi][ni][r] + bvs;
        if constexpr (EPI == EPI_BF16) {
          ((bf16_t*)Cv)[offC + (long)row * ldc + col] = (bf16_t)v;
        } else if constexpr (EPI == EPI_GELU_BF16) {
          ((bf16_t*)Cv)[offC + (long)row * ldc + col] = (bf16_t)gelu_f(v);
        } else if constexpr (EPI == EPI_GELU_F32) {
          ((float*)Cv)[offC + (long)row * ldc + col] = gelu_f(v);
        } else {  // EPI_RES_F32
          const long idx = offC + (long)row * ldc + col;
          ((float*)Cv)[idx] = res[idx] + v;
        }
      }
    }
  }
}

// ---------------------------------------------------------------------------
// Flash attention: grid (S/128, B*H). 4 independent waves per block, each owns
// 32 q-rows. Q in regs; K read from global (L2-resident); online softmax fully
// in-wave; P re-layout via per-wave swizzled LDS; PV reads vt (V^T) directly.
// O written in place over Q. No __syncthreads anywhere.
// ---------------------------------------------------------------------------
__global__ __launch_bounds__(256)
void flash_kernel(const bf16_t* __restrict__ q, const bf16_t* __restrict__ k,
                  const bf16_t* __restrict__ vt, bf16_t* __restrict__ o,
                  const int* __restrict__ xlen)
{
  __shared__ bf16_t plds[4][4096];   // per-wave 32x128 bf16, XOR-swizzled
  const int tid = threadIdx.x, w = tid >> 6, lane = tid & 63;
  const int lo = lane & 15, g = lane >> 4;
  const int bh = blockIdx.y, b = bh >> 3, h = bh & 7;
  const int q0 = blockIdx.x * 128 + w * 32;
  const int nv = xlen[b] >> 2;       // number of valid kv columns
  const long base = (long)b * 1048576 + (long)h * 128;
  const bf16_t* Qp = q + base;
  const bf16_t* Kp = k + base;
  const bf16_t* Vp = vt + (long)b * 1048576 + ((long)h << 17);  // rows d, stride 1024
  bf16_t* pb = plds[w];

  // Q fragments, held for the whole kernel: qf[mi][ks]
  bf16x8 qf[2][4];
#pragma unroll
  for (int mi = 0; mi < 2; ++mi)
#pragma unroll
    for (int ks = 0; ks < 4; ++ks)
      qf[mi][ks] = *reinterpret_cast<const bf16x8*>(
          Qp + (long)(q0 + mi * 16 + lo) * 1024 + ks * 32 + g * 8);

  floatx4 of[2][8] = {};
  float m[2][4], l[2][4];
#pragma unroll
  for (int mi = 0; mi < 2; ++mi)
#pragma unroll
    for (int r = 0; r < 4; ++r) { m[mi][r] = -1e30f; l[mi][r] = 0.0f; }

#pragma unroll 1
  for (int kt = 0; kt < 8; ++kt) {
    const int kv0 = kt * 128;
    // S = Q @ K^T (128 kv cols)
    floatx4 s[2][8] = {};
#pragma unroll
    for (int ni = 0; ni < 8; ++ni) {
      bf16x8 bv[4];
#pragma unroll
      for (int ks = 0; ks < 4; ++ks)
        bv[ks] = *reinterpret_cast<const bf16x8*>(
            Kp + (long)(kv0 + ni * 16 + lo) * 1024 + ks * 32 + g * 8);
#pragma unroll
      for (int ks = 0; ks < 4; ++ks) {
        s[0][ni] = MFMA16(qf[0][ks], bv[ks], s[0][ni]);
        s[1][ni] = MFMA16(qf[1][ks], bv[ks], s[1][ni]);
      }
    }
    // WAR guard: previous tile's P reads done before overwriting
    asm volatile("s_waitcnt lgkmcnt(0)" ::: "memory");
    // online softmax + P -> LDS (bf16, swizzled)
#pragma unroll
    for (int mi = 0; mi < 2; ++mi) {
#pragma unroll
      for (int r = 0; r < 4; ++r) {
        float vv[8]; float pm = -1e30f;
#pragma unroll
        for (int ni = 0; ni < 8; ++ni) {
          float val = s[mi][ni][r];
          if (kv0 + ni * 16 + lo >= nv) val = -1e30f;
          vv[ni] = val; pm = fmaxf(pm, val);
        }
        pm = fmaxf(pm, __shfl_xor(pm, 1)); pm = fmaxf(pm, __shfl_xor(pm, 2));
        pm = fmaxf(pm, __shfl_xor(pm, 4)); pm = fmaxf(pm, __shfl_xor(pm, 8));
        const float mo = m[mi][r];
        const float mn = fmaxf(mo, pm);
        const float sc = __expf(mo - mn);
        const int row = mi * 16 + g * 4 + r;
        const int swz = (row & 7) << 4;
        float ss = 0.0f;
#pragma unroll
        for (int ni = 0; ni < 8; ++ni) {
          const float p = __expf(vv[ni] - mn);
          ss += p;
          pb[row * 128 + ((((ni * 16 + lo) * 2) ^ swz) >> 1)] = (bf16_t)p;
        }
        ss += __shfl_xor(ss, 1); ss += __shfl_xor(ss, 2);
        ss += __shfl_xor(ss, 4); ss += __shfl_xor(ss, 8);
        l[mi][r] = l[mi][r] * sc + ss;
        m[mi][r] = mn;
#pragma unroll
        for (int nd = 0; nd < 8; ++nd) of[mi][nd][r] *= sc;
      }
    }
    // RAW guard: P writes visible before A-frag reads
    asm volatile("s_waitcnt lgkmcnt(0)" ::: "memory");
    // O += P @ V  (vt rows = d, k = kv)
#pragma unroll
    for (int ks = 0; ks < 4; ++ks) {
      bf16x8 av[2];
#pragma unroll
      for (int mi = 0; mi < 2; ++mi) {
        const int row = mi * 16 + lo;
        av[mi] = *reinterpret_cast<const bf16x8*>(
            pb + row * 128 + (((ks * 64 + g * 16) ^ ((row & 7) << 4)) >> 1));
      }
#pragma unroll
      for (int nd = 0; nd < 8; ++nd) {
        bf16x8 bv = *reinterpret_cast<const bf16x8*>(
            Vp + (long)(nd * 16 + lo) * 1024 + kv0 + ks * 32 + g * 8);
        of[0][nd] = MFMA16(av[0], bv, of[0][nd]);
        of[1][nd] = MFMA16(av[1], bv, of[1][nd]);
      }
    }
  }

  // epilogue: normalize and write O (in place over Q region)
#pragma unroll
  for (int mi = 0; mi < 2; ++mi)
#pragma unroll
    for (int r = 0; r < 4; ++r) {
      const float inv = 1.0f / l[mi][r];
      const long rb = base + (long)(q0 + mi * 16 + g * 4 + r) * 1024;
#pragma unroll
      for (int nd = 0; nd < 8; ++nd)
        o[rb + nd * 16 + lo] = (bf16_t)(of[mi][nd][r] * inv);
    }
}

// LayerNorm: one block per row of 1024 f32 -> bf16
__global__ __launch_bounds__(256)
void ln_kernel(const float* __restrict__ x, bf16_t* __restrict__ y,
               const float* __restrict__ w, const float* __restrict__ b)
{
  const long row = blockIdx.x;
  const float4 v = reinterpret_cast<const float4*>(x + row * ND)[threadIdx.x];
  float s  = v.x + v.y + v.z + v.w;
  float ss = v.x * v.x + v.y * v.y + v.z * v.z + v.w * v.w;
#pragma unroll
  for (int off = 32; off; off >>= 1) { s += __shfl_down(s, off); ss += __shfl_down(ss, off); }
  __shared__ float sh[8];
  if ((threadIdx.x & 63) == 0) { sh[threadIdx.x >> 6] = s; sh[4 + (threadIdx.x >> 6)] = ss; }
  __syncthreads();
  const float tot  = sh[0] + sh[1] + sh[2] + sh[3];
  const float tot2 = sh[4] + sh[5] + sh[6] + sh[7];
  const float mean = tot * (1.0f / ND);
  const float var  = tot2 * (1.0f / ND) - mean * mean;
  const float rstd = rsqrtf(var + 1e-5f);
  const int i0 = threadIdx.x * 4;
  const float vv[4] = {v.x, v.y, v.z, v.w};
  bf16x4 o;
#pragma unroll
  for (int j = 0; j < 4; ++j)
    o[j] = (bf16_t)((vv[j] - mean) * rstd * w[i0 + j] + b[i0 + j]);
  reinterpret_cast<bf16x4*>(y + row * ND)[threadIdx.x] = o;
}

// pre-scaled rope table: rtab[s*64+i] = (cos, sin)(s*f_i) * 128^-0.25
__global__ __launch_bounds__(256)
void rtab_kernel(float2* __restrict__ tab)
{
  const int idx = blockIdx.x * 256 + threadIdx.x;   // 65536
  const int s = idx >> 6, i = idx & 63;
  const float freq = __expf((float)i * -0.14391156831212787f);  // 10000^(-2i/128)
  float sn, cs;
  sincosf((float)s * freq, &sn, &cs);
  const float sc = 0.29730177875068026f;
  tab[idx] = make_float2(cs * sc, sn * sc);
}

// im2col conv1: A1[(b*2048+t), i*3+kk] = x[b, i, 2t+kk-1] (pad 1), f32->bf16
__global__ __launch_bounds__(256)
void im2col1_kernel(const float* __restrict__ x, bf16_t* __restrict__ a)
{
  const long idx = (long)blockIdx.x * 256 + threadIdx.x;
  if (idx >= (long)NB * NT1 * 384) return;
  const int  k = (int)(idx % 384);
  const long m = idx / 384;
  const int i = k / 3, kk = k - 3 * i;
  const int t = (int)(m & (NT1 - 1));
  const int b = (int)(m >> 11);
  const int tt = 2 * t + kk - 1;
  float v = 0.0f;
  if (tt >= 0 && tt < NT) v = x[((long)b * 128 + i) * NT + tt];
  a[idx] = (bf16_t)v;
}

// im2col conv2: A2[(b*1024+t), i*3+kk] = h1[b, 2t+kk-1, i] (pad 1)
__global__ __launch_bounds__(256)
void im2col2_kernel(const bf16_t* __restrict__ h1, bf16_t* __restrict__ a)
{
  const long idx = (long)blockIdx.x * 256 + threadIdx.x;
  if (idx >= (long)NB * NS * 3072) return;
  const int  k = (int)(idx % 3072);
  const long m = idx / 3072;
  const int i = k / 3, kk = k - 3 * i;
  const int t = (int)(m & (NS - 1));
  const int b = (int)(m >> 10);
  const int tt = 2 * t + kk - 1;
  bf16_t v = (bf16_t)0.0f;
  if (tt >= 0 && tt < NT1) v = h1[((long)b * NT1 + tt) * ND + i];
  a[idx] = v;
}

__global__ void ylen_kernel(const int* __restrict__ xlen, float* __restrict__ ylen)
{
  const int b = threadIdx.x;
  if (b < NB) {
    const int y1 = (xlen[b] + 1) >> 1;
    ylen[b] = (float)((y1 + 1) >> 1);
  }
}

__global__ __launch_bounds__(256)
void cvt_kernel(const float* __restrict__ in, bf16_t* __restrict__ out, long n)
{
  const long i = ((long)blockIdx.x * 256 + threadIdx.x) * 4;
  if (i >= n) return;
  const float4 v = *reinterpret_cast<const float4*>(in + i);
  bf16x4 o;
  o[0] = (bf16_t)v.x; o[1] = (bf16_t)v.y; o[2] = (bf16_t)v.z; o[3] = (bf16_t)v.w;
  *reinterpret_cast<bf16x4*>(out + i) = o;
}

// three 1M-element f32 arrays -> one contiguous 3M bf16 region
__global__ __launch_bounds__(256)
void cvt3_kernel(const float* __restrict__ a, const float* __restrict__ b,
                 const float* __restrict__ c, bf16_t* __restrict__ out)
{
  const long i = ((long)blockIdx.x * 256 + threadIdx.x) * 4;
  const float* src; long j;
  if (i < 1048576)      { src = a; j = i; }
  else if (i < 2097152) { src = b; j = i - 1048576; }
  else                  { src = c; j = i - 2097152; }
  const float4 v = *reinterpret_cast<const float4*>(src + j);
  bf16x4 o;
  o[0] = (bf16_t)v.x; o[1] = (bf16_t)v.y; o[2] = (bf16_t)v.z; o[3] = (bf16_t)v.w;
  *reinterpret_cast<bf16x4*>(out + i) = o;
}

// two 4M-element f32 arrays -> one contiguous 8M bf16 region
__global__ __launch_bounds__(256)
void cvt2_kernel(const float* __restrict__ a, const float* __restrict__ b,
                 bf16_t* __restrict__ out)
{
  const long i = ((long)blockIdx.x * 256 + threadIdx.x) * 4;
  const float* src; long j;
  if (i < 4194304) { src = a; j = i; }
  else             { src = b; j = i - 4194304; }
  const float4 v = *reinterpret_cast<const float4*>(src + j);
  bf16x4 o;
  o[0] = (bf16_t)v.x; o[1] = (bf16_t)v.y; o[2] = (bf16_t)v.z; o[3] = (bf16_t)v.w;
  *reinterpret_cast<bf16x4*>(out + i) = o;
}

extern "C" void kernel_launch(void* const* d_in, const int* in_sizes, int n_in,
                              void* d_out, int out_size, void* d_ws, size_t ws_size,
                              hipStream_t stream)
{
  const float* x         = (const float*)d_in[0];
  const int*   x_len     = (const int*)  d_in[1];
  const float* conv1_w   = (const float*)d_in[2];
  const float* conv1_b   = (const float*)d_in[3];
  const float* conv2_w   = (const float*)d_in[4];
  const float* conv2_b   = (const float*)d_in[5];
  const float* attn_ln_w = (const float*)d_in[6];
  const float* attn_ln_b = (const float*)d_in[7];
  const float* q_w   = (const float*)d_in[8];
  const float* q_b   = (const float*)d_in[9];
  const float* k_w   = (const float*)d_in[10];
  const float* v_w   = (const float*)d_in[11];
  const float* v_b   = (const float*)d_in[12];
  const float* out_w = (const float*)d_in[13];
  const float* out_b = (const float*)d_in[14];
  const float* mlp_ln_w = (const float*)d_in[15];
  const float* mlp_ln_b = (const float*)d_in[16];
  const float* mlp1_w = (const float*)d_in[17];
  const float* mlp1_b = (const float*)d_in[18];
  const float* mlp2_w = (const float*)d_in[19];
  const float* mlp2_b = (const float*)d_in[20];
  float* outp = (float*)d_out;
  (void)in_sizes; (void)n_in; (void)out_size;

  const long MB = 1024L * 1024;
  char* ws = (char*)d_ws;
  size_t off = 0;
  auto alloc = [&](size_t bytes) -> char* {
    char* p = ws + off;
    off += (bytes + 255) & ~(size_t)255;
    return p;
  };
  bf16_t* ybuf  = (bf16_t*)alloc(16 * MB);       //  16 MB | a1(conv)
  bf16_t* qbuf  = (bf16_t*)alloc(16 * MB);       //  16 MB | h1[0:16] | Q then O
  char*   R     = alloc(64 * MB);                //  64 MB | h1[16:32]+a2 | kbuf | hid
  char*   wA    = alloc(24 * MB);                //  24 MB | weights/vt/rtab
  const size_t required = off;

  // conv-phase aliases
  bf16_t* a1  = ybuf;                            // 12 MB
  bf16_t* h1  = qbuf;                            // 32 MB (qbuf + R[0:16])
  bf16_t* a2  = (bf16_t*)(R + 16 * MB);          // 48 MB
  bf16_t* c2w = (bf16_t*)wA;                     //  6 MB
  bf16_t* c1w = (bf16_t*)(wA + 8 * MB);          // 0.75 MB
  // persistent
  float2* rtab = (float2*)(wA + 6 * MB);         // 512 KB at [6:6.5], kept
  // layer-phase aliases
  bf16_t* wqkv = (bf16_t*)wA;                    // [0:6]
  bf16_t* vt   = (bf16_t*)(wA + 8 * MB);         // [8:24] during attention
  bf16_t* wo   = (bf16_t*)(wA + 16 * MB);        // [16:18] after flash
  bf16_t* w1b  = (bf16_t*)(wA + 8 * MB);         // [8:16] after attn-out
  bf16_t* w2b  = (bf16_t*)(wA + 16 * MB);        // [16:24]
  bf16_t* kbuf = (bf16_t*)R;                     // [0:16] during attention
  bf16_t* hid  = (bf16_t*)R;                     // 64 MB during MLP

  if (required > ws_size) {
    ylen_kernel<<<dim3(1), 64, 0, stream>>>(x_len, outp + 8L * 1024 * 1024);
    return;
  }

  auto cvt = [&](const float* in, bf16_t* o, long n) {
    cvt_kernel<<<dim3((unsigned)(n / 1024)), 256, 0, stream>>>(in, o, n);
  };

  rtab_kernel<<<dim3(256), 256, 0, stream>>>(rtab);

  // ---- conv stem ----
  cvt(conv1_w, c1w, 1024L * 384);
  cvt(conv2_w, c2w, 1024L * 3072);
  im2col1_kernel<<<dim3((unsigned)((16384L * 384) / 256)), 256, 0, stream>>>(x, a1);
  gemm_bt<EPI_GELU_BF16><<<dim3(128, 8, 1), 256, 0, stream>>>(
      a1, 384, 0, 0, c1w, 384, 0, 0, h1, 1024, 0, 0, conv1_b, nullptr, 384, 1, 1,
      nullptr, nullptr, nullptr, nullptr);
  im2col2_kernel<<<dim3((unsigned)((8192L * 3072) / 256)), 256, 0, stream>>>(h1, a2);
  gemm_bt<EPI_GELU_F32><<<dim3(64, 8, 1), 256, 0, stream>>>(
      a2, 3072, 0, 0, c2w, 3072, 0, 0, outp /*carry*/, 1024, 0, 0, conv2_b, nullptr, 3072, 1, 1,
      nullptr, nullptr, nullptr, nullptr);

  float* carry = outp;  // f32 residual stream lives in d_out

  for (int l = 0; l < 6; ++l) {
    cvt3_kernel<<<dim3(3072), 256, 0, stream>>>(
        q_w + (long)l * 1048576, k_w + (long)l * 1048576, v_w + (long)l * 1048576, wqkv);

    ln_kernel<<<dim3(8192), 256, 0, stream>>>(carry, ybuf, attn_ln_w + l * 1024, attn_ln_b + l * 1024);

    // fused QKV projection + rope/scale + V-transpose (N=3072)
    gemm_bt<EPI_QKV><<<dim3(64, 24, 1), 256, 0, stream>>>(
        ybuf, 1024, 0, 0, wqkv, 1024, 0, 0, qbuf, 1024, 0, 0,
        q_b + l * 1024, nullptr, 1024, 1, 1, kbuf, vt, v_b + l * 1024, rtab);

    // flash attention: O overwrites Q in place
    flash_kernel<<<dim3(8, 64), 256, 0, stream>>>(qbuf, kbuf, vt, qbuf, x_len);

    // carry += O @ ow^T + ob
    cvt(out_w + (long)l * 1048576, wo, 1048576);
    gemm_bt<EPI_RES_F32><<<dim3(64, 8, 1), 256, 0, stream>>>(
        qbuf, 1024, 0, 0, wo, 1024, 0, 0, carry, 1024, 0, 0,
        out_b + l * 1024, carry, 1024, 1, 1, nullptr, nullptr, nullptr, nullptr);

    cvt2_kernel<<<dim3(8192), 256, 0, stream>>>(
        mlp1_w + (long)l * 4194304, mlp2_w + (long)l * 4194304, w1b);

    ln_kernel<<<dim3(8192), 256, 0, stream>>>(carry, ybuf, mlp_ln_w + l * 1024, mlp_ln_b + l * 1024);

    gemm_bt<EPI_GELU_BF16><<<dim3(64, 32, 1), 256, 0, stream>>>(
        ybuf, 1024, 0, 0, w1b, 1024, 0, 0, hid, 4096, 0, 0,
        mlp1_b + (long)l * 4096, nullptr, 1024, 1, 1, nullptr, nullptr, nullptr, nullptr);
    gemm_bt<EPI_RES_F32><<<dim3(64, 8, 1), 256, 0, stream>>>(
        hid, 4096, 0, 0, w2b, 4096, 0, 0, carry, 1024, 0, 0,
        mlp2_b + l * 1024, carry, 4096, 1, 1, nullptr, nullptr, nullptr, nullptr);
  }

  ylen_kernel<<<dim3(1), 64, 0, stream>>>(x_len, outp + 8L * 1024 * 1024);
}

// Round 5
// 3543.263 us; speedup vs baseline: 1.1736x; 1.1736x over previous
//
#include <hip/hip_runtime.h>
#include <hip/hip_bf16.h>
#include <cstdint>
#include <cstddef>

// ---------------------------------------------------------------------------
// AudioEncoder (Whisper-style) forward for MI355X.
// B=8, T=4096, n_mels=128, D=1024, H=8 heads (hd=128), F=4096, L=6, S=1024.
// GEMMs: bf16 MFMA 128x128 tile, 2-phase double-buffered LDS.
// Attention: flash kernel with LDS-staged double-buffered K/V (KVBLK=64),
// XOR-swizzled layouts (linear gload_lds dest + inverse-swizzled source).
// ---------------------------------------------------------------------------

typedef __bf16 bf16_t;
typedef __bf16 bf16x8 __attribute__((ext_vector_type(8)));
typedef __bf16 bf16x4 __attribute__((ext_vector_type(4)));
typedef float  floatx4 __attribute__((ext_vector_type(4)));

#define NB   8
#define NS   1024
#define ND   1024
#define NT   4096
#define NT1  2048

#define MFMA16(a, b, c) __builtin_amdgcn_mfma_f32_16x16x32_bf16(a, b, c, 0, 0, 0)

__device__ __forceinline__ float gelu_f(float x) {
  return 0.5f * x * (1.0f + erff(x * 0.70710678118654752440f));
}

__device__ __forceinline__ void gload16(const void* g, void* l) {
  __builtin_amdgcn_global_load_lds(
      (__attribute__((address_space(1))) void*)(const_cast<void*>(g)),
      (__attribute__((address_space(3))) void*)l, 16, 0, 0);
}

enum { EPI_BF16 = 0, EPI_GELU_BF16 = 2, EPI_GELU_F32 = 3, EPI_RES_F32 = 4, EPI_QKV = 5 };

// C = A (M,K) @ B^T, B stored (N,K) row-major. 128x128 tile, 4 waves, each a
// 64x64 quadrant of 4x4 16x16x32-bf16 MFMA frags. 2-phase double-buffered LDS.
template<int EPI>
__global__ __launch_bounds__(256)
void gemm_bt(const bf16_t* __restrict__ A, long lda, long aHi, long aLo,
             const bf16_t* __restrict__ Bm, long ldb, long bHi, long bLo,
             void* Cv, long ldc, long cHi, long cLo,
             const float* __restrict__ bias, const float* res,
             int K, int bMod, int swz,
             bf16_t* out2, bf16_t* out3, const float* __restrict__ bias2,
             const float2* __restrict__ rtab)
{
  __shared__ bf16_t sA[2][128 * 32];
  __shared__ bf16_t sB[2][128 * 32];
  const int tid  = threadIdx.x;
  const int w    = tid >> 6;
  const int lane = tid & 63;
  const int z  = blockIdx.z;
  const int zq = z / bMod, zr = z % bMod;
  const bf16_t* Ab = A  + (long)zq * aHi + (long)zr * aLo;
  const bf16_t* Bb = Bm + (long)zq * bHi + (long)zr * bLo;
  const long offC  = (long)zq * cHi + (long)zr * cLo;

  int bx = blockIdx.x, by = blockIdx.y;
  if (swz) {               // bijective XCD-chunked remap (grid size % 8 == 0)
    const int gx = gridDim.x;
    const int n  = gx * gridDim.y;
    int id = bx + by * gx;
    id = (id & 7) * (n >> 3) + (id >> 3);
    bx = id % gx; by = id / gx;
  }
  const int m0 = bx * 128, n0 = by * 128;

  const int lrow = lane >> 2;        // 0..15
  const int lcol = (lane & 3) * 8;   // elem offset 0,8,16,24
  const int seg0 = w * 2;

  floatx4 acc[4][4] = {};
  const int wr = w >> 1, wc = w & 1;

  auto stage = [&](int kb, int buf) {
#pragma unroll
    for (int j = 0; j < 2; ++j) {
      const int seg = seg0 + j;
      gload16(Ab + (long)(m0 + seg * 16 + lrow) * lda + (kb + lcol), &sA[buf][seg * 512]);
      gload16(Bb + (long)(n0 + seg * 16 + lrow) * ldb + (kb + lcol), &sB[buf][seg * 512]);
    }
  };

  stage(0, 0);
  __syncthreads();
  int cur = 0;
  for (int kb = 0; kb < K; kb += 32) {
    if (kb + 32 < K) stage(kb + 32, cur ^ 1);
    bf16x8 av[4], bv[4];
#pragma unroll
    for (int i = 0; i < 4; ++i) {
      av[i] = *reinterpret_cast<const bf16x8*>(
          &sA[cur][(wr * 64 + i * 16 + (lane & 15)) * 32 + (lane >> 4) * 8]);
      bv[i] = *reinterpret_cast<const bf16x8*>(
          &sB[cur][(wc * 64 + i * 16 + (lane & 15)) * 32 + (lane >> 4) * 8]);
    }
#pragma unroll
    for (int mi = 0; mi < 4; ++mi)
#pragma unroll
      for (int ni = 0; ni < 4; ++ni)
        acc[mi][ni] = MFMA16(av[mi], bv[ni], acc[mi][ni]);
    __syncthreads();
    cur ^= 1;
  }

  if constexpr (EPI == EPI_QKV) {
    const int sect = n0 >> 10;        // 0=Q 1=K 2=V
#pragma unroll
    for (int ni = 0; ni < 4; ++ni) {
      const int col = n0 + wc * 64 + ni * 16 + (lane & 15);
      const int c10 = col & 1023;
      float bvs = 0.0f;
      if (sect == 0) bvs = bias[c10];
      else if (sect == 2) bvs = bias2[c10];
#pragma unroll
      for (int mi = 0; mi < 4; ++mi) {
#pragma unroll
        for (int r = 0; r < 4; ++r) {
          const int row = m0 + wr * 64 + mi * 16 + (lane >> 4) * 4 + r;
          const int s = row & 1023;
          float val = acc[mi][ni][r] + bvs;
          if (sect < 2) {             // rope + scale (table pre-scaled)
            const float2 t = rtab[(s << 6) + ((col & 127) >> 1)];
            const float p = __shfl_xor(val, 1);
            val = val * t.x + p * ((col & 1) ? t.y : -t.y);
            bf16_t* dst = sect ? out2 : (bf16_t*)Cv;
            dst[(long)row * 1024 + c10] = (bf16_t)val;
          } else {                    // vt[b][h*128+d][s]
            out3[((long)(row >> 10) << 20) + ((long)(col - 2048) << 10) + s] = (bf16_t)val;
          }
        }
      }
    }
    return;
  }

#pragma unroll
  for (int ni = 0; ni < 4; ++ni) {
    const int col = n0 + wc * 64 + ni * 16 + (lane & 15);
    const float bvs = bias ? bias[col] : 0.0f;
#pragma unroll
    for (int mi = 0; mi < 4; ++mi) {
#pragma unroll
      for (int r = 0; r < 4; ++r) {
        const int row = m0 + wr * 64 + mi * 16 + (lane >> 4) * 4 + r;
        float v = acc[mi][ni][r] + bvs;
        if constexpr (EPI == EPI_BF16) {
          ((bf16_t*)Cv)[offC + (long)row * ldc + col] = (bf16_t)v;
        } else if constexpr (EPI == EPI_GELU_BF16) {
          ((bf16_t*)Cv)[offC + (long)row * ldc + col] = (bf16_t)gelu_f(v);
        } else if constexpr (EPI == EPI_GELU_F32) {
          ((float*)Cv)[offC + (long)row * ldc + col] = gelu_f(v);
        } else {  // EPI_RES_F32
          const long idx = offC + (long)row * ldc + col;
          ((float*)Cv)[idx] = res[idx] + v;
        }
      }
    }
  }
}

// ---------------------------------------------------------------------------
// Flash attention: grid (S/128, B*H), 4 waves/block, wave owns 32 q-rows.
// K (64x128) and V^T (128x64) tiles staged via global_load_lds into
// double-buffered, XOR-swizzled LDS (linear dest + inverse-swizzled global
// source, same involution on reads). Online softmax in-wave; P via per-wave
// swizzled LDS. Early exit past the valid KV length.
// ---------------------------------------------------------------------------
__global__ __launch_bounds__(256)
void flash_kernel(const bf16_t* __restrict__ q, const bf16_t* __restrict__ k,
                  const bf16_t* __restrict__ vt, bf16_t* __restrict__ o,
                  const int* __restrict__ xlen)
{
  __shared__ bf16_t sK[2][4096];   // [kv=64][d=128], rows swizzled by (row&7)<<4
  __shared__ bf16_t sV[2][4096];   // [d=128][kv=64], rows swizzled by (row&7)<<4
  __shared__ bf16_t sP[4][2048];   // per-wave [q=32][kv=64], swizzled
  const int tid = threadIdx.x, w = tid >> 6, lane = tid & 63;
  const int lo = lane & 15, g = lane >> 4;
  const int bh = blockIdx.y, b = bh >> 3, h = bh & 7;
  const int q0 = blockIdx.x * 128 + w * 32;
  const int nv  = xlen[b] >> 2;            // valid kv columns (>= 512)
  const int nkt = (nv + 63) >> 6;          // tiles of 64
  const long base = (long)b * 1048576 + (long)h * 128;
  const bf16_t* Qp = q + base;
  const bf16_t* Kp = k + base;
  const bf16_t* Vp = vt + (long)b * 1048576 + ((long)h << 17);  // [d][s]

  // stage one K/V tile (swizzled source, linear LDS dest)
  auto stageKV = [&](int kt, int buf) {
    const int kv0 = kt << 6;
#pragma unroll
    for (int j = 0; j < 4; ++j) {
      const int seg = (w << 2) + j;                    // 0..15, wave-uniform
      {
        const int row = (seg << 2) + (lane >> 4);      // kv row 0..63
        const int col = ((lane & 15) << 3) ^ ((row & 7) << 3);
        gload16(Kp + (long)(kv0 + row) * 1024 + col, &sK[buf][seg * 512]);
      }
      {
        const int row = (seg << 3) + (lane >> 3);      // d row 0..127
        const int col = ((lane & 7) << 3) ^ ((row & 7) << 3);
        gload16(Vp + (long)row * 1024 + kv0 + col, &sV[buf][seg * 512]);
      }
    }
  };

  // Q fragments, held for the whole kernel
  bf16x8 qf[2][4];
#pragma unroll
  for (int mi = 0; mi < 2; ++mi)
#pragma unroll
    for (int ks = 0; ks < 4; ++ks)
      qf[mi][ks] = *reinterpret_cast<const bf16x8*>(
          Qp + (long)(q0 + mi * 16 + lo) * 1024 + ks * 32 + g * 8);

  floatx4 of[2][8] = {};
  float m[2][4], l[2][4];
#pragma unroll
  for (int mi = 0; mi < 2; ++mi)
#pragma unroll
    for (int r = 0; r < 4; ++r) { m[mi][r] = -1e30f; l[mi][r] = 0.0f; }

  const char* kbase = (const char*)&sK[0][0];
  const char* vbase = (const char*)&sV[0][0];
  char* pbase = (char*)&sP[w][0];
  const int swzL = (lo & 7) << 4;

  stageKV(0, 0);
  __syncthreads();
  int cur = 0;
#pragma unroll 1
  for (int kt = 0; kt < nkt; ++kt) {
    const int kv0 = kt << 6;
    if (kt + 1 < nkt) stageKV(kt + 1, cur ^ 1);

    // S = Q @ K^T over 64 kv cols
    floatx4 s[2][4] = {};
#pragma unroll
    for (int ni = 0; ni < 4; ++ni) {
#pragma unroll
      for (int ks = 0; ks < 4; ++ks) {
        const bf16x8 bv = *reinterpret_cast<const bf16x8*>(
            kbase + cur * 8192 + (ni * 16 + lo) * 256 + ((ks * 64 + (g << 4)) ^ swzL));
        s[0][ni] = MFMA16(qf[0][ks], bv, s[0][ni]);
        s[1][ni] = MFMA16(qf[1][ks], bv, s[1][ni]);
      }
    }

    // online softmax + P -> per-wave LDS (bf16, swizzled)
#pragma unroll
    for (int mi = 0; mi < 2; ++mi) {
#pragma unroll
      for (int r = 0; r < 4; ++r) {
        float vv[4]; float pm = -1e30f;
#pragma unroll
        for (int ni = 0; ni < 4; ++ni) {
          float val = s[mi][ni][r];
          if (kv0 + ni * 16 + lo >= nv) val = -1e30f;
          vv[ni] = val; pm = fmaxf(pm, val);
        }
        pm = fmaxf(pm, __shfl_xor(pm, 1)); pm = fmaxf(pm, __shfl_xor(pm, 2));
        pm = fmaxf(pm, __shfl_xor(pm, 4)); pm = fmaxf(pm, __shfl_xor(pm, 8));
        const float mo = m[mi][r];
        const float mn = fmaxf(mo, pm);
        const float sc = __expf(mo - mn);
        const int qrow = mi * 16 + g * 4 + r;
        const int sw = (qrow & 7) << 4;
        float ss = 0.0f;
#pragma unroll
        for (int ni = 0; ni < 4; ++ni) {
          const float p = __expf(vv[ni] - mn);
          ss += p;
          *(bf16_t*)(pbase + qrow * 128 + (((ni << 5) + (lo << 1)) ^ sw)) = (bf16_t)p;
        }
        ss += __shfl_xor(ss, 1); ss += __shfl_xor(ss, 2);
        ss += __shfl_xor(ss, 4); ss += __shfl_xor(ss, 8);
        l[mi][r] = l[mi][r] * sc + ss;
        m[mi][r] = mn;
#pragma unroll
        for (int nd = 0; nd < 8; ++nd) of[mi][nd][r] *= sc;
      }
    }

    // RAW: P writes visible before A-frag reads (rule 18: + sched_barrier)
    asm volatile("s_waitcnt lgkmcnt(0)" ::: "memory");
    __builtin_amdgcn_sched_barrier(0);

    // O += P @ V
#pragma unroll
    for (int ks = 0; ks < 2; ++ks) {
      bf16x8 av0 = *reinterpret_cast<const bf16x8*>(
          pbase + (0 * 16 + lo) * 128 + (((ks << 6) + (g << 4)) ^ swzL));
      bf16x8 av1 = *reinterpret_cast<const bf16x8*>(
          pbase + (1 * 16 + lo) * 128 + (((ks << 6) + (g << 4)) ^ swzL));
#pragma unroll
      for (int nd = 0; nd < 8; ++nd) {
        const bf16x8 bv = *reinterpret_cast<const bf16x8*>(
            vbase + cur * 8192 + (nd * 16 + lo) * 128 + (((ks << 6) + (g << 4)) ^ swzL));
        of[0][nd] = MFMA16(av0, bv, of[0][nd]);
        of[1][nd] = MFMA16(av1, bv, of[1][nd]);
      }
    }
    __syncthreads();   // drains gload (next tile ready) + all LDS reads done
    cur ^= 1;
  }

  // epilogue: normalize and write O (in place over Q region)
#pragma unroll
  for (int mi = 0; mi < 2; ++mi)
#pragma unroll
    for (int r = 0; r < 4; ++r) {
      const float inv = 1.0f / l[mi][r];
      const long rb = base + (long)(q0 + mi * 16 + g * 4 + r) * 1024;
#pragma unroll
      for (int nd = 0; nd < 8; ++nd)
        o[rb + nd * 16 + lo] = (bf16_t)(of[mi][nd][r] * inv);
    }
}

// LayerNorm: one block per row of 1024 f32 -> bf16
__global__ __launch_bounds__(256)
void ln_kernel(const float* __restrict__ x, bf16_t* __restrict__ y,
               const float* __restrict__ w, const float* __restrict__ b)
{
  const long row = blockIdx.x;
  const float4 v = reinterpret_cast<const float4*>(x + row * ND)[threadIdx.x];
  float s  = v.x + v.y + v.z + v.w;
  float ss = v.x * v.x + v.y * v.y + v.z * v.z + v.w * v.w;
#pragma unroll
  for (int off = 32; off; off >>= 1) { s += __shfl_down(s, off); ss += __shfl_down(ss, off); }
  __shared__ float sh[8];
  if ((threadIdx.x & 63) == 0) { sh[threadIdx.x >> 6] = s; sh[4 + (threadIdx.x >> 6)] = ss; }
  __syncthreads();
  const float tot  = sh[0] + sh[1] + sh[2] + sh[3];
  const float tot2 = sh[4] + sh[5] + sh[6] + sh[7];
  const float mean = tot * (1.0f / ND);
  const float var  = tot2 * (1.0f / ND) - mean * mean;
  const float rstd = rsqrtf(var + 1e-5f);
  const int i0 = threadIdx.x * 4;
  const float vv[4] = {v.x, v.y, v.z, v.w};
  bf16x4 o;
#pragma unroll
  for (int j = 0; j < 4; ++j)
    o[j] = (bf16_t)((vv[j] - mean) * rstd * w[i0 + j] + b[i0 + j]);
  reinterpret_cast<bf16x4*>(y + row * ND)[threadIdx.x] = o;
}

// pre-scaled rope table: rtab[s*64+i] = (cos, sin)(s*f_i) * 128^-0.25
__global__ __launch_bounds__(256)
void rtab_kernel(float2* __restrict__ tab)
{
  const int idx = blockIdx.x * 256 + threadIdx.x;   // 65536
  const int s = idx >> 6, i = idx & 63;
  const float freq = __expf((float)i * -0.14391156831212787f);  // 10000^(-2i/128)
  float sn, cs;
  sincosf((float)s * freq, &sn, &cs);
  const float sc = 0.29730177875068026f;
  tab[idx] = make_float2(cs * sc, sn * sc);
}

// im2col conv1: A1[(b*2048+t), i*3+kk] = x[b, i, 2t+kk-1] (pad 1), f32->bf16
__global__ __launch_bounds__(256)
void im2col1_kernel(const float* __restrict__ x, bf16_t* __restrict__ a)
{
  const long idx = (long)blockIdx.x * 256 + threadIdx.x;
  if (idx >= (long)NB * NT1 * 384) return;
  const int  k = (int)(idx % 384);
  const long m = idx / 384;
  const int i = k / 3, kk = k - 3 * i;
  const int t = (int)(m & (NT1 - 1));
  const int b = (int)(m >> 11);
  const int tt = 2 * t + kk - 1;
  float v = 0.0f;
  if (tt >= 0 && tt < NT) v = x[((long)b * 128 + i) * NT + tt];
  a[idx] = (bf16_t)v;
}

// im2col conv2: A2[(b*1024+t), i*3+kk] = h1[b, 2t+kk-1, i] (pad 1)
__global__ __launch_bounds__(256)
void im2col2_kernel(const bf16_t* __restrict__ h1, bf16_t* __restrict__ a)
{
  const long idx = (long)blockIdx.x * 256 + threadIdx.x;
  if (idx >= (long)NB * NS * 3072) return;
  const int  k = (int)(idx % 3072);
  const long m = idx / 3072;
  const int i = k / 3, kk = k - 3 * i;
  const int t = (int)(m & (NS - 1));
  const int b = (int)(m >> 10);
  const int tt = 2 * t + kk - 1;
  bf16_t v = (bf16_t)0.0f;
  if (tt >= 0 && tt < NT1) v = h1[((long)b * NT1 + tt) * ND + i];
  a[idx] = v;
}

__global__ void ylen_kernel(const int* __restrict__ xlen, float* __restrict__ ylen)
{
  const int b = threadIdx.x;
  if (b < NB) {
    const int y1 = (xlen[b] + 1) >> 1;
    ylen[b] = (float)((y1 + 1) >> 1);
  }
}

__global__ __launch_bounds__(256)
void cvt_kernel(const float* __restrict__ in, bf16_t* __restrict__ out, long n)
{
  const long i = ((long)blockIdx.x * 256 + threadIdx.x) * 4;
  if (i >= n) return;
  const float4 v = *reinterpret_cast<const float4*>(in + i);
  bf16x4 o;
  o[0] = (bf16_t)v.x; o[1] = (bf16_t)v.y; o[2] = (bf16_t)v.z; o[3] = (bf16_t)v.w;
  *reinterpret_cast<bf16x4*>(out + i) = o;
}

// three 1M-element f32 arrays -> one contiguous 3M bf16 region
__global__ __launch_bounds__(256)
void cvt3_kernel(const float* __restrict__ a, const float* __restrict__ b,
                 const float* __restrict__ c, bf16_t* __restrict__ out)
{
  const long i = ((long)blockIdx.x * 256 + threadIdx.x) * 4;
  const float* src; long j;
  if (i < 1048576)      { src = a; j = i; }
  else if (i < 2097152) { src = b; j = i - 1048576; }
  else                  { src = c; j = i - 2097152; }
  const float4 v = *reinterpret_cast<const float4*>(src + j);
  bf16x4 o;
  o[0] = (bf16_t)v.x; o[1] = (bf16_t)v.y; o[2] = (bf16_t)v.z; o[3] = (bf16_t)v.w;
  *reinterpret_cast<bf16x4*>(out + i) = o;
}

// two 4M-element f32 arrays -> one contiguous 8M bf16 region
__global__ __launch_bounds__(256)
void cvt2_kernel(const float* __restrict__ a, const float* __restrict__ b,
                 bf16_t* __restrict__ out)
{
  const long i = ((long)blockIdx.x * 256 + threadIdx.x) * 4;
  const float* src; long j;
  if (i < 4194304) { src = a; j = i; }
  else             { src = b; j = i - 4194304; }
  const float4 v = *reinterpret_cast<const float4*>(src + j);
  bf16x4 o;
  o[0] = (bf16_t)v.x; o[1] = (bf16_t)v.y; o[2] = (bf16_t)v.z; o[3] = (bf16_t)v.w;
  *reinterpret_cast<bf16x4*>(out + i) = o;
}

extern "C" void kernel_launch(void* const* d_in, const int* in_sizes, int n_in,
                              void* d_out, int out_size, void* d_ws, size_t ws_size,
                              hipStream_t stream)
{
  const float* x         = (const float*)d_in[0];
  const int*   x_len     = (const int*)  d_in[1];
  const float* conv1_w   = (const float*)d_in[2];
  const float* conv1_b   = (const float*)d_in[3];
  const float* conv2_w   = (const float*)d_in[4];
  const float* conv2_b   = (const float*)d_in[5];
  const float* attn_ln_w = (const float*)d_in[6];
  const float* attn_ln_b = (const float*)d_in[7];
  const float* q_w   = (const float*)d_in[8];
  const float* q_b   = (const float*)d_in[9];
  const float* k_w   = (const float*)d_in[10];
  const float* v_w   = (const float*)d_in[11];
  const float* v_b   = (const float*)d_in[12];
  const float* out_w = (const float*)d_in[13];
  const float* out_b = (const float*)d_in[14];
  const float* mlp_ln_w = (const float*)d_in[15];
  const float* mlp_ln_b = (const float*)d_in[16];
  const float* mlp1_w = (const float*)d_in[17];
  const float* mlp1_b = (const float*)d_in[18];
  const float* mlp2_w = (const float*)d_in[19];
  const float* mlp2_b = (const float*)d_in[20];
  float* outp = (float*)d_out;
  (void)in_sizes; (void)n_in; (void)out_size;

  const long MB = 1024L * 1024;
  char* ws = (char*)d_ws;
  size_t off = 0;
  auto alloc = [&](size_t bytes) -> char* {
    char* p = ws + off;
    off += (bytes + 255) & ~(size_t)255;
    return p;
  };
  bf16_t* ybuf  = (bf16_t*)alloc(16 * MB);       //  16 MB | a1(conv)
  bf16_t* qbuf  = (bf16_t*)alloc(16 * MB);       //  16 MB | h1[0:16] | Q then O
  char*   R     = alloc(64 * MB);                //  64 MB | h1[16:32]+a2 | kbuf | hid
  char*   wA    = alloc(24 * MB);                //  24 MB | weights/vt/rtab
  const size_t required = off;

  // conv-phase aliases
  bf16_t* a1  = ybuf;                            // 12 MB
  bf16_t* h1  = qbuf;                            // 32 MB (qbuf + R[0:16])
  bf16_t* a2  = (bf16_t*)(R + 16 * MB);          // 48 MB
  bf16_t* c2w = (bf16_t*)wA;                     //  6 MB
  bf16_t* c1w = (bf16_t*)(wA + 8 * MB);          // 0.75 MB
  // persistent
  float2* rtab = (float2*)(wA + 6 * MB);         // 512 KB at [6:6.5], kept
  // layer-phase aliases
  bf16_t* wqkv = (bf16_t*)wA;                    // [0:6]
  bf16_t* vt   = (bf16_t*)(wA + 8 * MB);         // [8:24] during attention
  bf16_t* wo   = (bf16_t*)(wA + 16 * MB);        // [16:18] after flash
  bf16_t* w1b  = (bf16_t*)(wA + 8 * MB);         // [8:16] after attn-out
  bf16_t* w2b  = (bf16_t*)(wA + 16 * MB);        // [16:24]
  bf16_t* kbuf = (bf16_t*)R;                     // [0:16] during attention
  bf16_t* hid  = (bf16_t*)R;                     // 64 MB during MLP

  if (required > ws_size) {
    ylen_kernel<<<dim3(1), 64, 0, stream>>>(x_len, outp + 8L * 1024 * 1024);
    return;
  }

  auto cvt = [&](const float* in, bf16_t* o, long n) {
    cvt_kernel<<<dim3((unsigned)(n / 1024)), 256, 0, stream>>>(in, o, n);
  };

  rtab_kernel<<<dim3(256), 256, 0, stream>>>(rtab);

  // ---- conv stem ----
  cvt(conv1_w, c1w, 1024L * 384);
  cvt(conv2_w, c2w, 1024L * 3072);
  im2col1_kernel<<<dim3((unsigned)((16384L * 384) / 256)), 256, 0, stream>>>(x, a1);
  gemm_bt<EPI_GELU_BF16><<<dim3(128, 8, 1), 256, 0, stream>>>(
      a1, 384, 0, 0, c1w, 384, 0, 0, h1, 1024, 0, 0, conv1_b, nullptr, 384, 1, 1,
      nullptr, nullptr, nullptr, nullptr);
  im2col2_kernel<<<dim3((unsigned)((8192L * 3072) / 256)), 256, 0, stream>>>(h1, a2);
  gemm_bt<EPI_GELU_F32><<<dim3(64, 8, 1), 256, 0, stream>>>(
      a2, 3072, 0, 0, c2w, 3072, 0, 0, outp /*carry*/, 1024, 0, 0, conv2_b, nullptr, 3072, 1, 1,
      nullptr, nullptr, nullptr, nullptr);

  float* carry = outp;  // f32 residual stream lives in d_out

  for (int l = 0; l < 6; ++l) {
    cvt3_kernel<<<dim3(3072), 256, 0, stream>>>(
        q_w + (long)l * 1048576, k_w + (long)l * 1048576, v_w + (long)l * 1048576, wqkv);

    ln_kernel<<<dim3(8192), 256, 0, stream>>>(carry, ybuf, attn_ln_w + l * 1024, attn_ln_b + l * 1024);

    // fused QKV projection + rope/scale + V-transpose (N=3072)
    gemm_bt<EPI_QKV><<<dim3(64, 24, 1), 256, 0, stream>>>(
        ybuf, 1024, 0, 0, wqkv, 1024, 0, 0, qbuf, 1024, 0, 0,
        q_b + l * 1024, nullptr, 1024, 1, 1, kbuf, vt, v_b + l * 1024, rtab);

    // flash attention: O overwrites Q in place
    flash_kernel<<<dim3(8, 64), 256, 0, stream>>>(qbuf, kbuf, vt, qbuf, x_len);

    // carry += O @ ow^T + ob
    cvt(out_w + (long)l * 1048576, wo, 1048576);
    gemm_bt<EPI_RES_F32><<<dim3(64, 8, 1), 256, 0, stream>>>(
        qbuf, 1024, 0, 0, wo, 1024, 0, 0, carry, 1024, 0, 0,
        out_b + l * 1024, carry, 1024, 1, 1, nullptr, nullptr, nullptr, nullptr);

    cvt2_kernel<<<dim3(8192), 256, 0, stream>>>(
        mlp1_w + (long)l * 4194304, mlp2_w + (long)l * 4194304, w1b);

    ln_kernel<<<dim3(8192), 256, 0, stream>>>(carry, ybuf, mlp_ln_w + l * 1024, mlp_ln_b + l * 1024);

    gemm_bt<EPI_GELU_BF16><<<dim3(64, 32, 1), 256, 0, stream>>>(
        ybuf, 1024, 0, 0, w1b, 1024, 0, 0, hid, 4096, 0, 0,
        mlp1_b + (long)l * 4096, nullptr, 1024, 1, 1, nullptr, nullptr, nullptr, nullptr);
    gemm_bt<EPI_RES_F32><<<dim3(64, 8, 1), 256, 0, stream>>>(
        hid, 4096, 0, 0, w2b, 4096, 0, 0, carry, 1024, 0, 0,
        mlp2_b + l * 1024, carry, 4096, 1, 1, nullptr, nullptr, nullptr, nullptr);
  }

  ylen_kernel<<<dim3(1), 64, 0, stream>>>(x_len, outp + 8L * 1024 * 1024);
}